// Round 1
// baseline (118.716 us; speedup 1.0000x reference)
//
#include <hip/hip_runtime.h>

#define NBATCH 16384
#define H 16
#define E 64

// One wave (64 threads) per batch element b.
// Per batch:  m = mean(others) (16x64);  mW = m @ W (16x64);
//             score = mW @ main^T (16x16); attn = softmax_g(score);
//             context = attn @ main (16x64).
// LDS strides padded (68 floats) so every ds_read_b128 pattern is <=2-way
// bank aliased (free on CDNA4). W (16KB) is read from global: it stays
// L1/L2 resident across all blocks.
__global__ __launch_bounds__(64) void ovo_kernel(
    const float* __restrict__ o0, const float* __restrict__ o1,
    const float* __restrict__ o2, const float* __restrict__ o3,
    const float* __restrict__ mn, const float* __restrict__ W,
    float* __restrict__ ctx_out, float* __restrict__ attn_out)
{
    __shared__ float sM[H][68];     // m rows; reused as sScore/sAttnT later
    __shared__ float sMain[H][68];  // main rows
    __shared__ float sMW[H][68];    // m @ W

    float (*sScore)[20] = (float (*)[20])(&sM[0][0]);        // 16x20 floats (row 80B, b128-aligned)
    float (*sAttnT)[16] = (float (*)[16])(&sM[0][0] + 320);  // 16x16 floats, base 1280B aligned

    const int l = threadIdx.x;
    const size_t base = (size_t)blockIdx.x * (H * E);

    // ---- Phase 1: load others -> mean into sM; main -> sMain (float4, coalesced)
#pragma unroll
    for (int k = 0; k < 4; ++k) {
        const int flat = k * 256 + l * 4;
        const int h = flat >> 6;
        const int e = flat & 63;
        float4 a = *(const float4*)(o0 + base + flat);
        float4 b = *(const float4*)(o1 + base + flat);
        float4 c = *(const float4*)(o2 + base + flat);
        float4 d = *(const float4*)(o3 + base + flat);
        float4 v = *(const float4*)(mn + base + flat);
        float4 m4;
        m4.x = (a.x + b.x + c.x + d.x) * 0.25f;
        m4.y = (a.y + b.y + c.y + d.y) * 0.25f;
        m4.z = (a.z + b.z + c.z + d.z) * 0.25f;
        m4.w = (a.w + b.w + c.w + d.w) * 0.25f;
        *(float4*)&sM[h][e] = m4;
        *(float4*)&sMain[h][e] = v;
    }
    __syncthreads();

    // ---- Phase 2: mW[h][f] = sum_e m[h][e] * W[e][f]   (lane = ht*16+ft, 4x4 tile)
    {
        const int ht = l >> 4, ft = l & 15;
        const int h0 = ht * 4, f0 = ft * 4;
        float acc[4][4] = {{0.f}};
#pragma unroll
        for (int e0 = 0; e0 < 64; e0 += 4) {
            float4 mrow[4], wrow[4];
#pragma unroll
            for (int i = 0; i < 4; ++i) mrow[i] = *(const float4*)&sM[h0 + i][e0];
#pragma unroll
            for (int j = 0; j < 4; ++j) wrow[j] = *(const float4*)&W[(e0 + j) * 64 + f0];
#pragma unroll
            for (int i = 0; i < 4; ++i) {
                const float* mr = (const float*)&mrow[i];
#pragma unroll
                for (int ee = 0; ee < 4; ++ee) {
                    const float* wr = (const float*)&wrow[ee];
#pragma unroll
                    for (int j = 0; j < 4; ++j)
                        acc[i][j] = fmaf(mr[ee], wr[j], acc[i][j]);
                }
            }
        }
#pragma unroll
        for (int i = 0; i < 4; ++i)
            *(float4*)&sMW[h0 + i][f0] =
                make_float4(acc[i][0], acc[i][1], acc[i][2], acc[i][3]);
    }
    __syncthreads();   // sMW visible; sM reads all done (sScore overlay now safe)

    // ---- Phase 3: score[h][g] = sum_f mW[h][f]*main[g][f]  (lane = hp*8+gp, 2x2 tile)
    {
        const int hp = l >> 3, gp = l & 7;
        const int h0 = hp * 2, g0 = gp * 2;
        float sc00 = 0.f, sc01 = 0.f, sc10 = 0.f, sc11 = 0.f;
#pragma unroll
        for (int f0 = 0; f0 < 64; f0 += 4) {
            float4 a0 = *(const float4*)&sMW[h0][f0];
            float4 a1 = *(const float4*)&sMW[h0 + 1][f0];
            float4 b0 = *(const float4*)&sMain[g0][f0];
            float4 b1 = *(const float4*)&sMain[g0 + 1][f0];
            const float* pa0 = (const float*)&a0;
            const float* pa1 = (const float*)&a1;
            const float* pb0 = (const float*)&b0;
            const float* pb1 = (const float*)&b1;
#pragma unroll
            for (int q = 0; q < 4; ++q) {
                sc00 = fmaf(pa0[q], pb0[q], sc00);
                sc01 = fmaf(pa0[q], pb1[q], sc01);
                sc10 = fmaf(pa1[q], pb0[q], sc10);
                sc11 = fmaf(pa1[q], pb1[q], sc11);
            }
        }
        *(float2*)&sScore[h0][g0]     = make_float2(sc00, sc01);
        *(float2*)&sScore[h0 + 1][g0] = make_float2(sc10, sc11);
    }
    __syncthreads();

    // ---- Phase 4: row softmax over g (lanes 0..15, lane = h); write attn + attnT
    if (l < 16) {
        float s[16];
        *(float4*)&s[0]  = *(const float4*)&sScore[l][0];
        *(float4*)&s[4]  = *(const float4*)&sScore[l][4];
        *(float4*)&s[8]  = *(const float4*)&sScore[l][8];
        *(float4*)&s[12] = *(const float4*)&sScore[l][12];
        float mx = s[0];
#pragma unroll
        for (int g = 1; g < 16; ++g) mx = fmaxf(mx, s[g]);
        float sum = 0.f;
#pragma unroll
        for (int g = 0; g < 16; ++g) { s[g] = __expf(s[g] - mx); sum += s[g]; }
        const float inv = 1.0f / sum;
#pragma unroll
        for (int g = 0; g < 16; ++g) s[g] *= inv;
#pragma unroll
        for (int g = 0; g < 16; ++g) sAttnT[g][l] = s[g];  // transposed for phase 5
        float* ap = attn_out + (size_t)blockIdx.x * (H * H) + l * 16;
#pragma unroll
        for (int c = 0; c < 4; ++c)
            *(float4*)(ap + 4 * c) =
                make_float4(s[4*c], s[4*c+1], s[4*c+2], s[4*c+3]);
    }
    __syncthreads();

    // ---- Phase 5: context[h][e] = sum_g attn[h][g]*main[g][e] (lane = ht*16+et, 4x4 tile)
    {
        const int ht = l >> 4, et = l & 15;
        const int h0 = ht * 4, e0 = et * 4;
        float acc[4][4] = {{0.f}};
#pragma unroll
        for (int g = 0; g < 16; ++g) {
            float4 av = *(const float4*)&sAttnT[g][h0];
            float4 bv = *(const float4*)&sMain[g][e0];
            const float* pa = (const float*)&av;
            const float* pb = (const float*)&bv;
#pragma unroll
            for (int i = 0; i < 4; ++i)
#pragma unroll
                for (int j = 0; j < 4; ++j)
                    acc[i][j] = fmaf(pa[i], pb[j], acc[i][j]);
        }
        float* cp = ctx_out + base;
#pragma unroll
        for (int i = 0; i < 4; ++i)
            *(float4*)(cp + (h0 + i) * 64 + e0) =
                make_float4(acc[i][0], acc[i][1], acc[i][2], acc[i][3]);
    }
}

extern "C" void kernel_launch(void* const* d_in, const int* in_sizes, int n_in,
                              void* d_out, int out_size, void* d_ws, size_t ws_size,
                              hipStream_t stream) {
    const float* o0 = (const float*)d_in[0];
    const float* o1 = (const float*)d_in[1];
    const float* o2 = (const float*)d_in[2];
    const float* o3 = (const float*)d_in[3];
    const float* mn = (const float*)d_in[4];
    const float* W  = (const float*)d_in[5];
    float* ctx  = (float*)d_out;
    float* attn = ctx + (size_t)NBATCH * H * E;
    hipLaunchKernelGGL(ovo_kernel, dim3(NBATCH), dim3(64), 0, stream,
                       o0, o1, o2, o3, mn, W, ctx, attn);
}